// Round 10
// baseline (212.347 us; speedup 1.0000x reference)
//
#include <hip/hip_runtime.h>
#include <hip/hip_bf16.h>

#define GPTR(p) ((__attribute__((address_space(1))) void*)(p))
#define LPTR(p) ((__attribute__((address_space(3))) void*)(p))

typedef __attribute__((ext_vector_type(8))) short short8;
typedef __attribute__((ext_vector_type(4))) float f32x4;
typedef __attribute__((ext_vector_type(16))) float f32x16;
typedef unsigned short u16t;
typedef unsigned int u32t;

#define NHEAD 16
#define DK 64
#define NF 1024
#define BB 4
#define TT 2048
#define BT (BB * TT) /* 8192 */

static __device__ __forceinline__ u16t f2bf(float f) {
  union { float f; unsigned u; } c; c.f = f;
  unsigned r = c.u + 0x7fffu + ((c.u >> 16) & 1u);
  return (u16t)(r >> 16);
}

static __device__ __forceinline__ u32t pkbf(float a, float b) {
  float2 ff; ff.x = a; ff.y = b;
  __hip_bfloat162 h2 = __float22bfloat162_rn(ff);
  u32t uu; __builtin_memcpy(&uu, &h2, 4);
  return uu;
}

__global__ void cvt_kernel(const float* __restrict__ src, u16t* __restrict__ dst, int n4) {
  int stride = gridDim.x * blockDim.x;
  for (int i = blockIdx.x * blockDim.x + threadIdx.x; i < n4; i += stride) {
    float4 f = reinterpret_cast<const float4*>(src)[i];
    ushort4 o;
    o.x = f2bf(f.x); o.y = f2bf(f.y); o.z = f2bf(f.z); o.w = f2bf(f.w);
    reinterpret_cast<ushort4*>(dst)[i] = o;
  }
}

// C = (A @ W^T + bias) * 0.125 * log2(e) ; bf16 out, fp32 acc
__launch_bounds__(256, 2)
__global__ void qproj_kernel(const u16t* __restrict__ A, const u16t* __restrict__ W,
                             const float* __restrict__ bias, u16t* __restrict__ C) {
  __shared__ u16t As[128 * 64];
  __shared__ u16t Bs[128 * 64];
  const int tid = threadIdx.x;
  const int m0 = blockIdx.x * 128;
  const int n0 = blockIdx.y * 128;
  const int w = tid >> 6, lane = tid & 63;
  const int wr = (w >> 1) * 64, wc = (w & 1) * 64;
  const int g = lane >> 4, r = lane & 15;

  f32x4 acc[4][4] = {};

  for (int kb = 0; kb < NF; kb += 64) {
    __syncthreads();
#pragma unroll
    for (int i = 0; i < 4; ++i) {
      int c = i * 256 + tid;
      int row = c >> 3, slot = c & 7;
      int gs = slot ^ (row & 7);
      __builtin_amdgcn_global_load_lds(GPTR(A + (size_t)(m0 + row) * NF + kb + gs * 8),
                                       LPTR(As + c * 8), 16, 0, 0);
    }
#pragma unroll
    for (int i = 0; i < 4; ++i) {
      int c = i * 256 + tid;
      int row = c >> 3, slot = c & 7;
      int gs = slot ^ (row & 7);
      __builtin_amdgcn_global_load_lds(GPTR(W + (size_t)(n0 + row) * NF + kb + gs * 8),
                                       LPTR(Bs + c * 8), 16, 0, 0);
    }
    __syncthreads();
#pragma unroll
    for (int kk = 0; kk < 2; ++kk) {
      short8 af[4], bfr[4];
#pragma unroll
      for (int i = 0; i < 4; ++i) {
        int row = wr + i * 16 + r;
        int slot = (4 * kk + g) ^ (row & 7);
        af[i] = *reinterpret_cast<const short8*>(As + row * 64 + slot * 8);
      }
#pragma unroll
      for (int j = 0; j < 4; ++j) {
        int row = wc + j * 16 + r;
        int slot = (4 * kk + g) ^ (row & 7);
        bfr[j] = *reinterpret_cast<const short8*>(Bs + row * 64 + slot * 8);
      }
#pragma unroll
      for (int i = 0; i < 4; ++i)
#pragma unroll
        for (int j = 0; j < 4; ++j)
          acc[i][j] = __builtin_amdgcn_mfma_f32_16x16x32_bf16(af[i], bfr[j], acc[i][j], 0, 0, 0);
    }
  }
#pragma unroll
  for (int i = 0; i < 4; ++i)
#pragma unroll
    for (int j = 0; j < 4; ++j) {
      int grow = m0 + wr + i * 16 + 4 * g;
      int gcol = n0 + wc + j * 16 + r;
      float bv = bias[gcol];
#pragma unroll
      for (int reg = 0; reg < 4; ++reg)
        C[(size_t)(grow + reg) * NF + gcol] = f2bf((acc[i][j][reg] + bv) * 0.18033688f);
    }
}

// Flash attention, swapped-QK^T. Block = ONE (b,h) x 512 q-rows, 16 waves x ONE
// 32-row q-tile each (4 waves/SIMD for latency hiding; was 8 waves x 2 tiles).
// 256 blocks = 1/CU; K/V fetch bounded by construction. R9's counted-wait
// 1-barrier schedule: ds_write V(t) -> s_waitcnt vmcnt(0) lgkmcnt(0) -> s_barrier
// -> issue K-DMA(t+1) [waves 0-7] + V-loads(t+1) [waves 8-15] -> compute(t).
// LDS 32KB: K dbuf @0/@8192 (row kv 128B, 16B-slot s = granule s^P(kv),
//   P(r)=(r+(r>>3))&7); V dbuf @16384/@24576 (row d 128B, 8B-slot s = kv-granule
//   s^(d&15)^((d>>4)&3)).
__launch_bounds__(1024, 4)
__global__ void attn_kernel(const u16t* __restrict__ Q, const u16t* __restrict__ K,
                            const u16t* __restrict__ V, const int* __restrict__ mask,
                            float* __restrict__ O) {
  __shared__ __attribute__((aligned(16))) char lds[32768];

  const int tid = threadIdx.x;          // 0..1023
  const int lane = tid & 63;
  const int w = tid >> 6;               // 0..15
  const int qc = lane & 31;             // q-col for S^T / d-col for PV output
  const int hi = lane >> 5;
  const int b = blockIdx.x >> 4, h = blockIdx.x & 15;
  const size_t bbase = (size_t)b * TT * NF;
  const int hoff = h * DK;
  const int qrow0 = blockIdx.y * 512 + w * 32;   // one 32-row q-tile per wave

  // Q B-frags (col=q=lane&31, k(d)=16t+8hi+e), one tile, whole kernel
  short8 qa[4];
#pragma unroll
  for (int t = 0; t < 4; ++t)
    qa[t] = *reinterpret_cast<const short8*>(
        Q + bbase + (size_t)(qrow0 + qc) * NF + hoff + 16 * t + 8 * hi);

  f32x16 oacc0 = {}, oacc1 = {};
  float lsum = 0.f;

  const int st = tid & 511;  // staging lane id (waves 0-7: K; waves 8-15: V)
  // K staging (DMA, waves 0-7): chunk = st, row = st>>3, pre-swizzled source
  const int srow = st >> 3;
  const int ksg = (st & 7) ^ ((srow + (srow >> 3)) & 7);
  const u16t* Ksrc = K + bbase + (size_t)srow * NF + hoff + ksg * 8;

  // V staging (waves 8-15): st = (Qv = st>>5, sub = (st>>4)&1, dq = st&15)
  const int Qv = st >> 5, sub = (st >> 4) & 1, dq = st & 15;
  const u16t* Vsrc = V + bbase + (size_t)(4 * Qv + 2 * sub) * NF + hoff + 4 * dq;
  const int slotbase = Qv ^ (dq >> 2) ^ (4 * (dq & 3));
  const int wbase = 4 * dq * 128 + (slotbase << 3) + 4 * sub;  // within V buffer

  const int* msrc = mask + b * TT + lane;

  // read-address bases (within buffers)
  const int P0 = (qc + (qc >> 3)) & 7;
  const int P1 = (P0 + 4) & 7;
  const int kB0 = qc * 128 + ((hi ^ P0) << 4);         // K row qc
  const int kB1 = qc * 128 + 4096 + ((hi ^ P1) << 4);  // K row qc+32
  const int g0 = hi ^ (qc & 15) ^ ((qc >> 4) & 3);
  const int vRb0 = qc * 128 + (g0 << 3);               // V col d=qc
  const int vRb1 = (qc + 32) * 128 + ((g0 ^ 2) << 3);  // V col d=qc+32

  // prologue: K(0) DMA by waves 0-7; V(0) reg-loads by waves 8-15; mask all
  uint2 va, vbl;
  if (w < 8) {
    __builtin_amdgcn_global_load_lds(GPTR(Ksrc), LPTR(lds + st * 16), 16, 0, 0);
    Ksrc += (size_t)64 * NF;
  } else {
    va = *reinterpret_cast<const uint2*>(Vsrc);
    vbl = *reinterpret_cast<const uint2*>(Vsrc + NF);
    Vsrc += (size_t)64 * NF;
  }
  int mv = msrc[0];

  for (int t2 = 0; t2 < TT; t2 += 64) {
    const int cb = (t2 >> 6) & 1;
    const int kbb = cb * 8192;          // current K buffer
    const int vbb = 16384 + cb * 8192;  // current V buffer

    if (w >= 8) { // write V(t) into V[cb] from regs
      u32t p0 = (va.x & 0xffffu) | (vbl.x << 16);
      u32t p1 = (va.x >> 16) | (vbl.x & 0xffff0000u);
      u32t p2 = (va.y & 0xffffu) | (vbl.y << 16);
      u32t p3 = (va.y >> 16) | (vbl.y & 0xffff0000u);
      *reinterpret_cast<u32t*>(lds + vbb + (wbase ^ 0) + 0) = p0;
      *reinterpret_cast<u32t*>(lds + vbb + (wbase ^ 8) + 128) = p1;
      *reinterpret_cast<u32t*>(lds + vbb + (wbase ^ 16) + 256) = p2;
      *reinterpret_cast<u32t*>(lds + vbb + (wbase ^ 24) + 384) = p3;
    }
    unsigned long long bm = __ballot(mv != 0);
    // counted-wait barrier: K-DMA(t) + V ds_writes drained; K-DMA is a full
    // compute-phase old in steady state.
    asm volatile("s_waitcnt vmcnt(0) lgkmcnt(0)" ::: "memory");
    __builtin_amdgcn_s_barrier();

    if (t2 + 64 < TT) {  // prefetch t+1: entire compute(t) to land
      if (w < 8) {
        __builtin_amdgcn_global_load_lds(GPTR(Ksrc), LPTR(lds + (kbb ^ 8192) + st * 16), 16, 0, 0);
        Ksrc += (size_t)64 * NF;
      } else {
        va = *reinterpret_cast<const uint2*>(Vsrc);
        vbl = *reinterpret_cast<const uint2*>(Vsrc + NF);
        Vsrc += (size_t)64 * NF;
      }
      mv = msrc[t2 + 64];
    }

    // QK^T for this wave's q-tile
    f32x16 s0 = {}, s1 = {};
#pragma unroll
    for (int t = 0; t < 4; ++t) {
      short8 kf0 = *reinterpret_cast<const short8*>(lds + kbb + (kB0 ^ (t << 5)));
      short8 kf1 = *reinterpret_cast<const short8*>(lds + kbb + (kB1 ^ (t << 5)));
      s0 = __builtin_amdgcn_mfma_f32_32x32x16_bf16(kf0, qa[t], s0, 0, 0, 0);
      s1 = __builtin_amdgcn_mfma_f32_32x32x16_bf16(kf1, qa[t], s1, 0, 0, 0);
    }

    // softmax + pack + PV per kv-16-slice t
    const u32t bmlo = (u32t)(bm >> (4 * hi));
    const u32t bmhi = (u32t)(bm >> (32 + 4 * hi));
#pragma unroll
    for (int t = 0; t < 4; ++t) {
      const u32t bms = (t < 2) ? bmlo : bmhi;
      union { u32t u[4]; short8 s; } pa;
      float eA = 0.f;
#pragma unroll
      for (int i = 0; i < 4; ++i) {
        const int reg = (t & 1) * 8 + 2 * i;
        const int bit = (reg & 3) + 8 * (reg >> 2);
        float xa = ((bms >> bit) & 1u) ? (t < 2 ? s0[reg] : s1[reg]) : -100.f;
        float xb = ((bms >> (bit + 1)) & 1u) ? (t < 2 ? s0[reg + 1] : s1[reg + 1]) : -100.f;
        xa = __builtin_exp2f(xa);
        xb = __builtin_exp2f(xb);
        eA += xa + xb;
        pa.u[i] = pkbf(xa, xb);
      }
      lsum += eA;
      union { uint2 u2[2]; short8 s; } vf0, vf1;
      vf0.u2[0] = *reinterpret_cast<const uint2*>(lds + vbb + (vRb0 ^ ((4 * t) << 3)));
      vf0.u2[1] = *reinterpret_cast<const uint2*>(lds + vbb + (vRb0 ^ (((4 * t) ^ 2) << 3)));
      vf1.u2[0] = *reinterpret_cast<const uint2*>(lds + vbb + (vRb1 ^ ((4 * t) << 3)));
      vf1.u2[1] = *reinterpret_cast<const uint2*>(lds + vbb + (vRb1 ^ (((4 * t) ^ 2) << 3)));
      oacc0 = __builtin_amdgcn_mfma_f32_32x32x16_bf16(pa.s, vf0.s, oacc0, 0, 0, 0);
      oacc1 = __builtin_amdgcn_mfma_f32_32x32x16_bf16(pa.s, vf1.s, oacc1, 0, 0, 0);
    }
  }

  // O[q][d]: C-layout row = (reg&3)+8*(reg>>2)+4hi, col = qc (+32)
  float lall = lsum + __shfl_xor(lsum, 32, 64);
  float linv = 1.0f / lall;
#pragma unroll
  for (int reg = 0; reg < 16; ++reg) {
    const int crow = (reg & 3) + 8 * (reg >> 2) + 4 * hi;
    float rl = __shfl(linv, crow, 64);
    float* orow = O + bbase + (size_t)(qrow0 + crow) * NF + hoff + qc;
    orow[0] = oacc0[reg] * rl;
    orow[32] = oacc1[reg] * rl;
  }
}

extern "C" void kernel_launch(void* const* d_in, const int* in_sizes, int n_in,
                              void* d_out, int out_size, void* d_ws, size_t ws_size,
                              hipStream_t stream) {
  const float* query = (const float*)d_in[0];
  const float* key   = (const float*)d_in[1];
  const float* value = (const float*)d_in[2];
  const int*   mask  = (const int*)d_in[3];
  const float* Wq    = (const float*)d_in[4];
  const float* bq    = (const float*)d_in[5];
  float* out = (float*)d_out;

  u16t* ws = (u16t*)d_ws;
  u16t* qb = ws;
  u16t* kb = ws + (size_t)8 * 1024 * 1024;
  u16t* vb = ws + (size_t)16 * 1024 * 1024;
  u16t* wb = ws + (size_t)24 * 1024 * 1024;
  u16t* qp = ws + (size_t)25 * 1024 * 1024;

  cvt_kernel<<<2048, 256, 0, stream>>>(query, qb, (BT * NF) / 4);
  cvt_kernel<<<2048, 256, 0, stream>>>(key,   kb, (BT * NF) / 4);
  cvt_kernel<<<2048, 256, 0, stream>>>(value, vb, (BT * NF) / 4);
  cvt_kernel<<<1024, 256, 0, stream>>>(Wq,    wb, (NF * NF) / 4);

  qproj_kernel<<<dim3(BT / 128, NF / 128), 256, 0, stream>>>(qb, wb, bq, qp);
  // grid: x = (b,h), y = q-pair; 4 q-blocks of one (b,h) share an XCD (flat%8 = x%8)
  attn_kernel<<<dim3(BB * NHEAD, TT / 512), 1024, 0, stream>>>(qp, kb, vb, mask, out);
}

// Round 11
// 155.966 us; speedup vs baseline: 1.3615x; 1.3615x over previous
//
#include <hip/hip_runtime.h>
#include <hip/hip_bf16.h>

#define GPTR(p) ((__attribute__((address_space(1))) void*)(p))
#define LPTR(p) ((__attribute__((address_space(3))) void*)(p))

typedef __attribute__((ext_vector_type(8))) short short8;
typedef __attribute__((ext_vector_type(4))) float f32x4;
typedef __attribute__((ext_vector_type(16))) float f32x16;
typedef unsigned short u16t;
typedef unsigned int u32t;

#define NHEAD 16
#define DK 64
#define NF 1024
#define BB 4
#define TT 2048
#define BT (BB * TT) /* 8192 */

static __device__ __forceinline__ u16t f2bf(float f) {
  union { float f; unsigned u; } c; c.f = f;
  unsigned r = c.u + 0x7fffu + ((c.u >> 16) & 1u);
  return (u16t)(r >> 16);
}

static __device__ __forceinline__ u32t pkbf(float a, float b) {
  float2 ff; ff.x = a; ff.y = b;
  __hip_bfloat162 h2 = __float22bfloat162_rn(ff);
  u32t uu; __builtin_memcpy(&uu, &h2, 4);
  return uu;
}

__global__ void cvt_kernel(const float* __restrict__ src, u16t* __restrict__ dst, int n4) {
  int stride = gridDim.x * blockDim.x;
  for (int i = blockIdx.x * blockDim.x + threadIdx.x; i < n4; i += stride) {
    float4 f = reinterpret_cast<const float4*>(src)[i];
    ushort4 o;
    o.x = f2bf(f.x); o.y = f2bf(f.y); o.z = f2bf(f.z); o.w = f2bf(f.w);
    reinterpret_cast<ushort4*>(dst)[i] = o;
  }
}

// C = (A @ W^T + bias) * 0.125 * log2(e) ; bf16 out, fp32 acc
__launch_bounds__(256, 2)
__global__ void qproj_kernel(const u16t* __restrict__ A, const u16t* __restrict__ W,
                             const float* __restrict__ bias, u16t* __restrict__ C) {
  __shared__ u16t As[128 * 64];
  __shared__ u16t Bs[128 * 64];
  const int tid = threadIdx.x;
  const int m0 = blockIdx.x * 128;
  const int n0 = blockIdx.y * 128;
  const int w = tid >> 6, lane = tid & 63;
  const int wr = (w >> 1) * 64, wc = (w & 1) * 64;
  const int g = lane >> 4, r = lane & 15;

  f32x4 acc[4][4] = {};

  for (int kb = 0; kb < NF; kb += 64) {
    __syncthreads();
#pragma unroll
    for (int i = 0; i < 4; ++i) {
      int c = i * 256 + tid;
      int row = c >> 3, slot = c & 7;
      int gs = slot ^ (row & 7);
      __builtin_amdgcn_global_load_lds(GPTR(A + (size_t)(m0 + row) * NF + kb + gs * 8),
                                       LPTR(As + c * 8), 16, 0, 0);
    }
#pragma unroll
    for (int i = 0; i < 4; ++i) {
      int c = i * 256 + tid;
      int row = c >> 3, slot = c & 7;
      int gs = slot ^ (row & 7);
      __builtin_amdgcn_global_load_lds(GPTR(W + (size_t)(n0 + row) * NF + kb + gs * 8),
                                       LPTR(Bs + c * 8), 16, 0, 0);
    }
    __syncthreads();
#pragma unroll
    for (int kk = 0; kk < 2; ++kk) {
      short8 af[4], bfr[4];
#pragma unroll
      for (int i = 0; i < 4; ++i) {
        int row = wr + i * 16 + r;
        int slot = (4 * kk + g) ^ (row & 7);
        af[i] = *reinterpret_cast<const short8*>(As + row * 64 + slot * 8);
      }
#pragma unroll
      for (int j = 0; j < 4; ++j) {
        int row = wc + j * 16 + r;
        int slot = (4 * kk + g) ^ (row & 7);
        bfr[j] = *reinterpret_cast<const short8*>(Bs + row * 64 + slot * 8);
      }
#pragma unroll
      for (int i = 0; i < 4; ++i)
#pragma unroll
        for (int j = 0; j < 4; ++j)
          acc[i][j] = __builtin_amdgcn_mfma_f32_16x16x32_bf16(af[i], bfr[j], acc[i][j], 0, 0, 0);
    }
  }
#pragma unroll
  for (int i = 0; i < 4; ++i)
#pragma unroll
    for (int j = 0; j < 4; ++j) {
      int grow = m0 + wr + i * 16 + 4 * g;
      int gcol = n0 + wc + j * 16 + r;
      float bv = bias[gcol];
#pragma unroll
      for (int reg = 0; reg < 4; ++reg)
        C[(size_t)(grow + reg) * NF + gcol] = f2bf((acc[i][j][reg] + bv) * 0.18033688f);
    }
}

// Flash attention, swapped-QK^T: 8 waves; block = ONE (b,h) x 512 q-rows (2 q-tiles
// of 256 per staged K/V tile). 256 blocks = 1/CU; K/V fetch bounded by construction.
// R9 schedule (counted-wait, ONE barrier/tile): ds_write K+V(t) -> s_waitcnt
// vmcnt(0) lgkmcnt(0) -> s_barrier -> issue fp32 K/V loads(t+1) (full compute
// phase to land; cvt at WRITE time so loads stay in flight) -> compute(t).
// K/V cvt fused: reads ORIGINAL fp32 key/value (cvt kernels dropped).
// LDS 32KB: K dbuf @0/@8192 (row kv 128B, 16B-slot s = granule s^P(kv),
//   P(r)=(r+(r>>3))&7); V dbuf @16384/@24576 (row d 128B, 8B-slot s = kv-granule
//   s^(d&15)^((d>>4)&3)).
__launch_bounds__(512, 2)
__global__ void attn_kernel(const u16t* __restrict__ Q, const float* __restrict__ K,
                            const float* __restrict__ V, const int* __restrict__ mask,
                            float* __restrict__ O) {
  __shared__ __attribute__((aligned(16))) char lds[32768];

  const int tid = threadIdx.x;
  const int lane = tid & 63;
  const int w = tid >> 6;
  const int qc = lane & 31;   // q-col for S^T / d-col for PV output
  const int hi = lane >> 5;
  const int b = blockIdx.x >> 4, h = blockIdx.x & 15;
  const size_t bbase = (size_t)b * TT * NF;
  const int hoff = h * DK;
  const int qrow0 = blockIdx.y * 512 + w * 32;   // q-tile 0; tile 1 at +256

  // Q B-frags (col=q=lane&31, k(d)=16t+8hi+e), both q-tiles, whole kernel
  short8 qa[2][4];
#pragma unroll
  for (int qt = 0; qt < 2; ++qt)
#pragma unroll
    for (int t = 0; t < 4; ++t)
      qa[qt][t] = *reinterpret_cast<const short8*>(
          Q + bbase + (size_t)(qrow0 + 256 * qt + qc) * NF + hoff + 16 * t + 8 * hi);

  f32x16 oacc[2][2] = {};
  float lsumA = 0.f, lsumB = 0.f;

  // K staging (fp32 reg-stage): chunk = tid -> LDS tid*16 (8 bf16); source row
  // tid>>3, col granule pre-swizzled (same bytes as R9's DMA+pre-swizzled src)
  const int srow = tid >> 3;
  const int ksg = (tid & 7) ^ ((srow + (srow >> 3)) & 7);
  const float* Ksrc = K + bbase + (size_t)srow * NF + hoff + ksg * 8;

  // V staging (fp32): thread = (Qv = tid>>5, sub = (tid>>4)&1, dq = tid&15)
  const int Qv = tid >> 5, sub = (tid >> 4) & 1, dq = tid & 15;
  const float* Vsrc = V + bbase + (size_t)(4 * Qv + 2 * sub) * NF + hoff + 4 * dq;
  const int slotbase = Qv ^ (dq >> 2) ^ (4 * (dq & 3));
  const int wbase = 4 * dq * 128 + (slotbase << 3) + 4 * sub;  // within V buffer

  const int* msrc = mask + b * TT + lane;

  // read-address bases (within buffers)
  const int P0 = (qc + (qc >> 3)) & 7;
  const int P1 = (P0 + 4) & 7;
  const int kB0 = qc * 128 + ((hi ^ P0) << 4);         // K row qc
  const int kB1 = qc * 128 + 4096 + ((hi ^ P1) << 4);  // K row qc+32
  const int g0 = hi ^ (qc & 15) ^ ((qc >> 4) & 3);
  const int vRb0 = qc * 128 + (g0 << 3);               // V col d=qc
  const int vRb1 = (qc + 32) * 128 + ((g0 ^ 2) << 3);  // V col d=qc+32

  // prologue: tile-0 fp32 loads into registers (cvt deferred to write)
  float4 kf32a = *reinterpret_cast<const float4*>(Ksrc);
  float4 kf32b = *reinterpret_cast<const float4*>(Ksrc + 4);
  float4 vf32a = *reinterpret_cast<const float4*>(Vsrc);
  float4 vf32b = *reinterpret_cast<const float4*>(Vsrc + NF);
  int mv = msrc[0];
  Ksrc += (size_t)64 * NF; Vsrc += (size_t)64 * NF;

  for (int t2 = 0; t2 < TT; t2 += 64) {
    const int cb = (t2 >> 6) & 1;
    const int kbb = cb * 8192;          // current K buffer
    const int vbb = 16384 + cb * 8192;  // current V buffer

    { // write K(t): cvt fp32->bf16 here (loads had full prior compute to land)
      union { u32t u[4]; int4 i4; } kw;
      kw.u[0] = pkbf(kf32a.x, kf32a.y);
      kw.u[1] = pkbf(kf32a.z, kf32a.w);
      kw.u[2] = pkbf(kf32b.x, kf32b.y);
      kw.u[3] = pkbf(kf32b.z, kf32b.w);
      *reinterpret_cast<int4*>(lds + kbb + tid * 16) = kw.i4;
    }
    { // write V(t): b64 granule (Qv, d), word sub; 2-way banked (free)
      u32t p0 = pkbf(vf32a.x, vf32b.x);
      u32t p1 = pkbf(vf32a.y, vf32b.y);
      u32t p2 = pkbf(vf32a.z, vf32b.z);
      u32t p3 = pkbf(vf32a.w, vf32b.w);
      *reinterpret_cast<u32t*>(lds + vbb + (wbase ^ 0) + 0) = p0;
      *reinterpret_cast<u32t*>(lds + vbb + (wbase ^ 8) + 128) = p1;
      *reinterpret_cast<u32t*>(lds + vbb + (wbase ^ 16) + 256) = p2;
      *reinterpret_cast<u32t*>(lds + vbb + (wbase ^ 24) + 384) = p3;
    }
    unsigned long long bm = __ballot(mv != 0);
    // counted-wait barrier: staging ds_writes drained (lgkm); vmcnt covers the
    // already-consumed reg loads.
    asm volatile("s_waitcnt vmcnt(0) lgkmcnt(0)" ::: "memory");
    __builtin_amdgcn_s_barrier();

    if (t2 + 64 < TT) {  // prefetch t+1 fp32: entire compute(t) to land
      kf32a = *reinterpret_cast<const float4*>(Ksrc);
      kf32b = *reinterpret_cast<const float4*>(Ksrc + 4);
      vf32a = *reinterpret_cast<const float4*>(Vsrc);
      vf32b = *reinterpret_cast<const float4*>(Vsrc + NF);
      mv = msrc[t2 + 64];
      Ksrc += (size_t)64 * NF; Vsrc += (size_t)64 * NF;
    }

    // QK^T: K-frags shared across both q-tiles
    f32x16 sA0 = {}, sA1 = {}, sB0 = {}, sB1 = {};
#pragma unroll
    for (int t = 0; t < 4; ++t) {
      short8 kf0 = *reinterpret_cast<const short8*>(lds + kbb + (kB0 ^ (t << 5)));
      short8 kf1 = *reinterpret_cast<const short8*>(lds + kbb + (kB1 ^ (t << 5)));
      sA0 = __builtin_amdgcn_mfma_f32_32x32x16_bf16(kf0, qa[0][t], sA0, 0, 0, 0);
      sA1 = __builtin_amdgcn_mfma_f32_32x32x16_bf16(kf1, qa[0][t], sA1, 0, 0, 0);
      sB0 = __builtin_amdgcn_mfma_f32_32x32x16_bf16(kf0, qa[1][t], sB0, 0, 0, 0);
      sB1 = __builtin_amdgcn_mfma_f32_32x32x16_bf16(kf1, qa[1][t], sB1, 0, 0, 0);
    }

    // softmax + pack + PV per kv-16-slice t; V-frags shared across q-tiles
    const u32t bmlo = (u32t)(bm >> (4 * hi));
    const u32t bmhi = (u32t)(bm >> (32 + 4 * hi));
#pragma unroll
    for (int t = 0; t < 4; ++t) {
      const u32t bms = (t < 2) ? bmlo : bmhi;
      union { u32t u[4]; short8 s; } pA, pB;
      float eA = 0.f, eB = 0.f;
#pragma unroll
      for (int i = 0; i < 4; ++i) {
        const int reg = (t & 1) * 8 + 2 * i;
        const int bit = (reg & 3) + 8 * (reg >> 2);
        const bool ma = (bms >> bit) & 1u;
        const bool mb = (bms >> (bit + 1)) & 1u;
        float xa = ma ? (t < 2 ? sA0[reg] : sA1[reg]) : -100.f;
        float xb = mb ? (t < 2 ? sA0[reg + 1] : sA1[reg + 1]) : -100.f;
        float ya = ma ? (t < 2 ? sB0[reg] : sB1[reg]) : -100.f;
        float yb = mb ? (t < 2 ? sB0[reg + 1] : sB1[reg + 1]) : -100.f;
        xa = __builtin_exp2f(xa); xb = __builtin_exp2f(xb);
        ya = __builtin_exp2f(ya); yb = __builtin_exp2f(yb);
        eA += xa + xb; eB += ya + yb;
        pA.u[i] = pkbf(xa, xb);
        pB.u[i] = pkbf(ya, yb);
      }
      lsumA += eA; lsumB += eB;
      union { uint2 u2[2]; short8 s; } vf0, vf1;
      vf0.u2[0] = *reinterpret_cast<const uint2*>(lds + vbb + (vRb0 ^ ((4 * t) << 3)));
      vf0.u2[1] = *reinterpret_cast<const uint2*>(lds + vbb + (vRb0 ^ (((4 * t) ^ 2) << 3)));
      vf1.u2[0] = *reinterpret_cast<const uint2*>(lds + vbb + (vRb1 ^ ((4 * t) << 3)));
      vf1.u2[1] = *reinterpret_cast<const uint2*>(lds + vbb + (vRb1 ^ (((4 * t) ^ 2) << 3)));
      oacc[0][0] = __builtin_amdgcn_mfma_f32_32x32x16_bf16(pA.s, vf0.s, oacc[0][0], 0, 0, 0);
      oacc[0][1] = __builtin_amdgcn_mfma_f32_32x32x16_bf16(pA.s, vf1.s, oacc[0][1], 0, 0, 0);
      oacc[1][0] = __builtin_amdgcn_mfma_f32_32x32x16_bf16(pB.s, vf0.s, oacc[1][0], 0, 0, 0);
      oacc[1][1] = __builtin_amdgcn_mfma_f32_32x32x16_bf16(pB.s, vf1.s, oacc[1][1], 0, 0, 0);
    }
  }

  // O[q][d]: C-layout row = (reg&3)+8*(reg>>2)+4hi, col = qc (+32)
#pragma unroll
  for (int qt = 0; qt < 2; ++qt) {
    float lsq = qt ? lsumB : lsumA;
    float lall = lsq + __shfl_xor(lsq, 32, 64);
    float linv = 1.0f / lall;
#pragma unroll
    for (int reg = 0; reg < 16; ++reg) {
      const int crow = (reg & 3) + 8 * (reg >> 2) + 4 * hi;
      float rl = __shfl(linv, crow, 64);
      float* orow = O + bbase + (size_t)(qrow0 + 256 * qt + crow) * NF + hoff + qc;
      orow[0] = oacc[qt][0][reg] * rl;
      orow[32] = oacc[qt][1][reg] * rl;
    }
  }
}

extern "C" void kernel_launch(void* const* d_in, const int* in_sizes, int n_in,
                              void* d_out, int out_size, void* d_ws, size_t ws_size,
                              hipStream_t stream) {
  const float* query = (const float*)d_in[0];
  const float* key   = (const float*)d_in[1];
  const float* value = (const float*)d_in[2];
  const int*   mask  = (const int*)d_in[3];
  const float* Wq    = (const float*)d_in[4];
  const float* bq    = (const float*)d_in[5];
  float* out = (float*)d_out;

  u16t* ws = (u16t*)d_ws;
  u16t* qb = ws;                                   // bf16 query (8M elems)
  u16t* wb = ws + (size_t)8 * 1024 * 1024;         // bf16 Wq    (1M elems)
  u16t* qp = ws + (size_t)9 * 1024 * 1024;         // bf16 q-proj (8M elems)

  cvt_kernel<<<2048, 256, 0, stream>>>(query, qb, (BT * NF) / 4);
  cvt_kernel<<<1024, 256, 0, stream>>>(Wq,    wb, (NF * NF) / 4);

  qproj_kernel<<<dim3(BT / 128, NF / 128), 256, 0, stream>>>(qb, wb, bq, qp);
  // grid: x = (b,h), y = q-pair; 4 q-blocks of one (b,h) share an XCD (flat%8 = x%8)
  attn_kernel<<<dim3(BB * NHEAD, TT / 512), 512, 0, stream>>>(qp, key, value, mask, out);
}

// Round 12
// 151.952 us; speedup vs baseline: 1.3975x; 1.0264x over previous
//
#include <hip/hip_runtime.h>
#include <hip/hip_bf16.h>

#define GPTR(p) ((__attribute__((address_space(1))) void*)(p))
#define LPTR(p) ((__attribute__((address_space(3))) void*)(p))

typedef __attribute__((ext_vector_type(8))) short short8;
typedef __attribute__((ext_vector_type(4))) float f32x4;
typedef __attribute__((ext_vector_type(16))) float f32x16;
typedef unsigned short u16t;
typedef unsigned int u32t;

#define NHEAD 16
#define DK 64
#define NF 1024
#define BB 4
#define TT 2048
#define BT (BB * TT) /* 8192 */

static __device__ __forceinline__ u16t f2bf(float f) {
  union { float f; unsigned u; } c; c.f = f;
  unsigned r = c.u + 0x7fffu + ((c.u >> 16) & 1u);
  return (u16t)(r >> 16);
}

static __device__ __forceinline__ u32t pkbf(float a, float b) {
  float2 ff; ff.x = a; ff.y = b;
  __hip_bfloat162 h2 = __float22bfloat162_rn(ff);
  u32t uu; __builtin_memcpy(&uu, &h2, 4);
  return uu;
}

__global__ void cvt_kernel(const float* __restrict__ src, u16t* __restrict__ dst, int n4) {
  int stride = gridDim.x * blockDim.x;
  for (int i = blockIdx.x * blockDim.x + threadIdx.x; i < n4; i += stride) {
    float4 f = reinterpret_cast<const float4*>(src)[i];
    ushort4 o;
    o.x = f2bf(f.x); o.y = f2bf(f.y); o.z = f2bf(f.z); o.w = f2bf(f.w);
    reinterpret_cast<ushort4*>(dst)[i] = o;
  }
}

// C = (A_fp32 @ W^T + bias) * 0.125 * log2(e) ; query cvt FUSED (reg-stage A with
// pkbf at ds_write; A-prefetch issued after barrier 2 so it flies during compute).
__launch_bounds__(256, 1)
__global__ void qproj_kernel(const float* __restrict__ A, const u16t* __restrict__ W,
                             const float* __restrict__ bias, u16t* __restrict__ C) {
  __shared__ u16t As[128 * 64];
  __shared__ u16t Bs[128 * 64];
  const int tid = threadIdx.x;
  const int m0 = blockIdx.x * 128;
  const int n0 = blockIdx.y * 128;
  const int w = tid >> 6, lane = tid & 63;
  const int wr = (w >> 1) * 64, wc = (w & 1) * 64;
  const int g = lane >> 4, r = lane & 15;

  f32x4 acc[4][4] = {};

  // A staging map: chunk c = i*256+tid; row = c>>3, slot = c&7, gs = slot^(row&7)
  float4 a0[4], a1[4];
#pragma unroll
  for (int i = 0; i < 4; ++i) {
    int c = i * 256 + tid;
    int row = c >> 3, slot = c & 7;
    int gs = slot ^ (row & 7);
    const float* src = A + (size_t)(m0 + row) * NF + gs * 8;
    a0[i] = *reinterpret_cast<const float4*>(src);
    a1[i] = *reinterpret_cast<const float4*>(src + 4);
  }

  for (int kb = 0; kb < NF; kb += 64) {
    __syncthreads();
#pragma unroll
    for (int i = 0; i < 4; ++i) {
      int c = i * 256 + tid;
      int row = c >> 3, slot = c & 7;
      int gs = slot ^ (row & 7);
      __builtin_amdgcn_global_load_lds(GPTR(W + (size_t)(n0 + row) * NF + kb + gs * 8),
                                       LPTR(Bs + c * 8), 16, 0, 0);
    }
#pragma unroll
    for (int i = 0; i < 4; ++i) {  // write A(kb) from regs, cvt here
      int c = i * 256 + tid;
      union { u32t u[4]; int4 i4; } kw;
      kw.u[0] = pkbf(a0[i].x, a0[i].y);
      kw.u[1] = pkbf(a0[i].z, a0[i].w);
      kw.u[2] = pkbf(a1[i].x, a1[i].y);
      kw.u[3] = pkbf(a1[i].z, a1[i].w);
      *reinterpret_cast<int4*>(reinterpret_cast<char*>(As) + c * 16) = kw.i4;
    }
    __syncthreads();  // drains W-DMA + A ds_writes
    if (kb + 64 < NF) {  // prefetch A(kb+64): flies during compute
#pragma unroll
      for (int i = 0; i < 4; ++i) {
        int c = i * 256 + tid;
        int row = c >> 3, slot = c & 7;
        int gs = slot ^ (row & 7);
        const float* src = A + (size_t)(m0 + row) * NF + kb + 64 + gs * 8;
        a0[i] = *reinterpret_cast<const float4*>(src);
        a1[i] = *reinterpret_cast<const float4*>(src + 4);
      }
    }
#pragma unroll
    for (int kk = 0; kk < 2; ++kk) {
      short8 af[4], bfr[4];
#pragma unroll
      for (int i = 0; i < 4; ++i) {
        int row = wr + i * 16 + r;
        int slot = (4 * kk + g) ^ (row & 7);
        af[i] = *reinterpret_cast<const short8*>(As + row * 64 + slot * 8);
      }
#pragma unroll
      for (int j = 0; j < 4; ++j) {
        int row = wc + j * 16 + r;
        int slot = (4 * kk + g) ^ (row & 7);
        bfr[j] = *reinterpret_cast<const short8*>(Bs + row * 64 + slot * 8);
      }
#pragma unroll
      for (int i = 0; i < 4; ++i)
#pragma unroll
        for (int j = 0; j < 4; ++j)
          acc[i][j] = __builtin_amdgcn_mfma_f32_16x16x32_bf16(af[i], bfr[j], acc[i][j], 0, 0, 0);
    }
  }
#pragma unroll
  for (int i = 0; i < 4; ++i)
#pragma unroll
    for (int j = 0; j < 4; ++j) {
      int grow = m0 + wr + i * 16 + 4 * g;
      int gcol = n0 + wc + j * 16 + r;
      float bv = bias[gcol];
#pragma unroll
      for (int reg = 0; reg < 4; ++reg)
        C[(size_t)(grow + reg) * NF + gcol] = f2bf((acc[i][j][reg] + bv) * 0.18033688f);
    }
}

// Flash attention, swapped-QK^T: 8 waves; block = ONE (b,h) x 512 q-rows (2 q-tiles
// of 256 per staged K/V tile). 256 blocks = 1/CU; K/V fetch bounded by construction.
// R11 schedule + MASK-AS-C-INIT: QK^T accumulators seeded with 0/-10000 per kv-row
// (32 cndmask once per tile) instead of 64 per-element selects in the softmax loop;
// masked exp2 underflows to exactly 0 — numerics unchanged.
// LDS 32KB: K dbuf @0/@8192 (row kv 128B, 16B-slot s = granule s^P(kv),
//   P(r)=(r+(r>>3))&7); V dbuf @16384/@24576 (row d 128B, 8B-slot s = kv-granule
//   s^(d&15)^((d>>4)&3)).
__launch_bounds__(512, 2)
__global__ void attn_kernel(const u16t* __restrict__ Q, const float* __restrict__ K,
                            const float* __restrict__ V, const int* __restrict__ mask,
                            float* __restrict__ O) {
  __shared__ __attribute__((aligned(16))) char lds[32768];

  const int tid = threadIdx.x;
  const int lane = tid & 63;
  const int w = tid >> 6;
  const int qc = lane & 31;   // q-col for S^T / d-col for PV output
  const int hi = lane >> 5;
  const int b = blockIdx.x >> 4, h = blockIdx.x & 15;
  const size_t bbase = (size_t)b * TT * NF;
  const int hoff = h * DK;
  const int qrow0 = blockIdx.y * 512 + w * 32;   // q-tile 0; tile 1 at +256

  // Q B-frags (col=q=lane&31, k(d)=16t+8hi+e), both q-tiles, whole kernel
  short8 qa[2][4];
#pragma unroll
  for (int qt = 0; qt < 2; ++qt)
#pragma unroll
    for (int t = 0; t < 4; ++t)
      qa[qt][t] = *reinterpret_cast<const short8*>(
          Q + bbase + (size_t)(qrow0 + 256 * qt + qc) * NF + hoff + 16 * t + 8 * hi);

  f32x16 oacc[2][2] = {};
  float lsumA = 0.f, lsumB = 0.f;

  // K staging (fp32 reg-stage): chunk = tid -> LDS tid*16 (8 bf16)
  const int srow = tid >> 3;
  const int ksg = (tid & 7) ^ ((srow + (srow >> 3)) & 7);
  const float* Ksrc = K + bbase + (size_t)srow * NF + hoff + ksg * 8;

  // V staging (fp32): thread = (Qv = tid>>5, sub = (tid>>4)&1, dq = tid&15)
  const int Qv = tid >> 5, sub = (tid >> 4) & 1, dq = tid & 15;
  const float* Vsrc = V + bbase + (size_t)(4 * Qv + 2 * sub) * NF + hoff + 4 * dq;
  const int slotbase = Qv ^ (dq >> 2) ^ (4 * (dq & 3));
  const int wbase = 4 * dq * 128 + (slotbase << 3) + 4 * sub;  // within V buffer

  const int* msrc = mask + b * TT + lane;

  // read-address bases (within buffers)
  const int P0 = (qc + (qc >> 3)) & 7;
  const int P1 = (P0 + 4) & 7;
  const int kB0 = qc * 128 + ((hi ^ P0) << 4);         // K row qc
  const int kB1 = qc * 128 + 4096 + ((hi ^ P1) << 4);  // K row qc+32
  const int g0 = hi ^ (qc & 15) ^ ((qc >> 4) & 3);
  const int vRb0 = qc * 128 + (g0 << 3);               // V col d=qc
  const int vRb1 = (qc + 32) * 128 + ((g0 ^ 2) << 3);  // V col d=qc+32

  // prologue: tile-0 fp32 loads into registers (cvt deferred to write)
  float4 kf32a = *reinterpret_cast<const float4*>(Ksrc);
  float4 kf32b = *reinterpret_cast<const float4*>(Ksrc + 4);
  float4 vf32a = *reinterpret_cast<const float4*>(Vsrc);
  float4 vf32b = *reinterpret_cast<const float4*>(Vsrc + NF);
  int mv = msrc[0];
  Ksrc += (size_t)64 * NF; Vsrc += (size_t)64 * NF;

  for (int t2 = 0; t2 < TT; t2 += 64) {
    const int cb = (t2 >> 6) & 1;
    const int kbb = cb * 8192;          // current K buffer
    const int vbb = 16384 + cb * 8192;  // current V buffer

    { // write K(t): cvt fp32->bf16 here (loads had full prior compute to land)
      union { u32t u[4]; int4 i4; } kw;
      kw.u[0] = pkbf(kf32a.x, kf32a.y);
      kw.u[1] = pkbf(kf32a.z, kf32a.w);
      kw.u[2] = pkbf(kf32b.x, kf32b.y);
      kw.u[3] = pkbf(kf32b.z, kf32b.w);
      *reinterpret_cast<int4*>(lds + kbb + tid * 16) = kw.i4;
    }
    { // write V(t): b64 granule (Qv, d), word sub; 2-way banked (free)
      u32t p0 = pkbf(vf32a.x, vf32b.x);
      u32t p1 = pkbf(vf32a.y, vf32b.y);
      u32t p2 = pkbf(vf32a.z, vf32b.z);
      u32t p3 = pkbf(vf32a.w, vf32b.w);
      *reinterpret_cast<u32t*>(lds + vbb + (wbase ^ 0) + 0) = p0;
      *reinterpret_cast<u32t*>(lds + vbb + (wbase ^ 8) + 128) = p1;
      *reinterpret_cast<u32t*>(lds + vbb + (wbase ^ 16) + 256) = p2;
      *reinterpret_cast<u32t*>(lds + vbb + (wbase ^ 24) + 384) = p3;
    }
    unsigned long long bm = __ballot(mv != 0);
    asm volatile("s_waitcnt vmcnt(0) lgkmcnt(0)" ::: "memory");
    __builtin_amdgcn_s_barrier();

    if (t2 + 64 < TT) {  // prefetch t+1 fp32: entire compute(t) to land
      kf32a = *reinterpret_cast<const float4*>(Ksrc);
      kf32b = *reinterpret_cast<const float4*>(Ksrc + 4);
      vf32a = *reinterpret_cast<const float4*>(Vsrc);
      vf32b = *reinterpret_cast<const float4*>(Vsrc + NF);
      mv = msrc[t2 + 64];
      Ksrc += (size_t)64 * NF; Vsrc += (size_t)64 * NF;
    }

    // mask-as-C-init: bias[kv-row] = masked ? -10000 : 0 (exp2 -> exactly 0)
    const u32t bmlo = (u32t)(bm >> (4 * hi));
    const u32t bmhi = (u32t)(bm >> (32 + 4 * hi));
    f32x16 bias0, bias1;
#pragma unroll
    for (int reg = 0; reg < 16; ++reg) {
      const int bit = (reg & 3) + 8 * (reg >> 2);
      bias0[reg] = ((bmlo >> bit) & 1u) ? 0.f : -10000.f;
      bias1[reg] = ((bmhi >> bit) & 1u) ? 0.f : -10000.f;
    }

    // QK^T: K-frags shared across both q-tiles; t=0 seeds with bias
    f32x16 sA0, sA1, sB0, sB1;
    {
      short8 kf0 = *reinterpret_cast<const short8*>(lds + kbb + kB0);
      short8 kf1 = *reinterpret_cast<const short8*>(lds + kbb + kB1);
      sA0 = __builtin_amdgcn_mfma_f32_32x32x16_bf16(kf0, qa[0][0], bias0, 0, 0, 0);
      sA1 = __builtin_amdgcn_mfma_f32_32x32x16_bf16(kf1, qa[0][0], bias1, 0, 0, 0);
      sB0 = __builtin_amdgcn_mfma_f32_32x32x16_bf16(kf0, qa[1][0], bias0, 0, 0, 0);
      sB1 = __builtin_amdgcn_mfma_f32_32x32x16_bf16(kf1, qa[1][0], bias1, 0, 0, 0);
    }
#pragma unroll
    for (int t = 1; t < 4; ++t) {
      short8 kf0 = *reinterpret_cast<const short8*>(lds + kbb + (kB0 ^ (t << 5)));
      short8 kf1 = *reinterpret_cast<const short8*>(lds + kbb + (kB1 ^ (t << 5)));
      sA0 = __builtin_amdgcn_mfma_f32_32x32x16_bf16(kf0, qa[0][t], sA0, 0, 0, 0);
      sA1 = __builtin_amdgcn_mfma_f32_32x32x16_bf16(kf1, qa[0][t], sA1, 0, 0, 0);
      sB0 = __builtin_amdgcn_mfma_f32_32x32x16_bf16(kf0, qa[1][t], sB0, 0, 0, 0);
      sB1 = __builtin_amdgcn_mfma_f32_32x32x16_bf16(kf1, qa[1][t], sB1, 0, 0, 0);
    }

    // softmax + pack + PV per kv-16-slice t (no mask ops — bias already applied)
#pragma unroll
    for (int t = 0; t < 4; ++t) {
      union { u32t u[4]; short8 s; } pA, pB;
      float eA = 0.f, eB = 0.f;
#pragma unroll
      for (int i = 0; i < 4; ++i) {
        const int reg = (t & 1) * 8 + 2 * i;
        float xa = __builtin_exp2f(t < 2 ? sA0[reg] : sA1[reg]);
        float xb = __builtin_exp2f(t < 2 ? sA0[reg + 1] : sA1[reg + 1]);
        float ya = __builtin_exp2f(t < 2 ? sB0[reg] : sB1[reg]);
        float yb = __builtin_exp2f(t < 2 ? sB0[reg + 1] : sB1[reg + 1]);
        eA += xa + xb; eB += ya + yb;
        pA.u[i] = pkbf(xa, xb);
        pB.u[i] = pkbf(ya, yb);
      }
      lsumA += eA; lsumB += eB;
      union { uint2 u2[2]; short8 s; } vf0, vf1;
      vf0.u2[0] = *reinterpret_cast<const uint2*>(lds + vbb + (vRb0 ^ ((4 * t) << 3)));
      vf0.u2[1] = *reinterpret_cast<const uint2*>(lds + vbb + (vRb0 ^ (((4 * t) ^ 2) << 3)));
      vf1.u2[0] = *reinterpret_cast<const uint2*>(lds + vbb + (vRb1 ^ ((4 * t) << 3)));
      vf1.u2[1] = *reinterpret_cast<const uint2*>(lds + vbb + (vRb1 ^ (((4 * t) ^ 2) << 3)));
      oacc[0][0] = __builtin_amdgcn_mfma_f32_32x32x16_bf16(pA.s, vf0.s, oacc[0][0], 0, 0, 0);
      oacc[0][1] = __builtin_amdgcn_mfma_f32_32x32x16_bf16(pA.s, vf1.s, oacc[0][1], 0, 0, 0);
      oacc[1][0] = __builtin_amdgcn_mfma_f32_32x32x16_bf16(pB.s, vf0.s, oacc[1][0], 0, 0, 0);
      oacc[1][1] = __builtin_amdgcn_mfma_f32_32x32x16_bf16(pB.s, vf1.s, oacc[1][1], 0, 0, 0);
    }
  }

  // O[q][d]: C-layout row = (reg&3)+8*(reg>>2)+4hi, col = qc (+32)
#pragma unroll
  for (int qt = 0; qt < 2; ++qt) {
    float lsq = qt ? lsumB : lsumA;
    float lall = lsq + __shfl_xor(lsq, 32, 64);
    float linv = 1.0f / lall;
#pragma unroll
    for (int reg = 0; reg < 16; ++reg) {
      const int crow = (reg & 3) + 8 * (reg >> 2) + 4 * hi;
      float rl = __shfl(linv, crow, 64);
      float* orow = O + bbase + (size_t)(qrow0 + 256 * qt + crow) * NF + hoff + qc;
      orow[0] = oacc[qt][0][reg] * rl;
      orow[32] = oacc[qt][1][reg] * rl;
    }
  }
}

extern "C" void kernel_launch(void* const* d_in, const int* in_sizes, int n_in,
                              void* d_out, int out_size, void* d_ws, size_t ws_size,
                              hipStream_t stream) {
  const float* query = (const float*)d_in[0];
  const float* key   = (const float*)d_in[1];
  const float* value = (const float*)d_in[2];
  const int*   mask  = (const int*)d_in[3];
  const float* Wq    = (const float*)d_in[4];
  const float* bq    = (const float*)d_in[5];
  float* out = (float*)d_out;

  u16t* ws = (u16t*)d_ws;
  u16t* wb = ws;                                   // bf16 Wq     (1M elems)
  u16t* qp = ws + (size_t)1024 * 1024;             // bf16 q-proj (8M elems)

  cvt_kernel<<<1024, 256, 0, stream>>>(Wq, wb, (NF * NF) / 4);

  qproj_kernel<<<dim3(BT / 128, NF / 128), 256, 0, stream>>>(query, wb, bq, qp);
  // grid: x = (b,h), y = q-pair; 4 q-blocks of one (b,h) share an XCD (flat%8 = x%8)
  attn_kernel<<<dim3(BB * NHEAD, TT / 512), 512, 0, stream>>>(qp, key, value, mask, out);
}

// Round 13
// 103.457 us; speedup vs baseline: 2.0525x; 1.4687x over previous
//
#include <hip/hip_runtime.h>
#include <hip/hip_bf16.h>

#define GPTR(p) ((__attribute__((address_space(1))) void*)(p))
#define LPTR(p) ((__attribute__((address_space(3))) void*)(p))

typedef __attribute__((ext_vector_type(8))) short short8;
typedef __attribute__((ext_vector_type(4))) float f32x4;
typedef __attribute__((ext_vector_type(16))) float f32x16;
typedef unsigned short u16t;
typedef unsigned int u32t;

#define NHEAD 16
#define DK 64
#define NF 1024
#define BB 4
#define TT 2048
#define BT (BB * TT) /* 8192 */

static __device__ __forceinline__ u16t f2bf(float f) {
  union { float f; unsigned u; } c; c.f = f;
  unsigned r = c.u + 0x7fffu + ((c.u >> 16) & 1u);
  return (u16t)(r >> 16);
}

static __device__ __forceinline__ u32t pkbf(float a, float b) {
  float2 ff; ff.x = a; ff.y = b;
  __hip_bfloat162 h2 = __float22bfloat162_rn(ff);
  u32t uu; __builtin_memcpy(&uu, &h2, 4);
  return uu;
}

__global__ void cvt_kernel(const float* __restrict__ src, u16t* __restrict__ dst, int n4) {
  int stride = gridDim.x * blockDim.x;
  for (int i = blockIdx.x * blockDim.x + threadIdx.x; i < n4; i += stride) {
    float4 f = reinterpret_cast<const float4*>(src)[i];
    ushort4 o;
    o.x = f2bf(f.x); o.y = f2bf(f.y); o.z = f2bf(f.z); o.w = f2bf(f.w);
    reinterpret_cast<ushort4*>(dst)[i] = o;
  }
}

// Per-batch order-preserving compaction of unmasked kv indices (deterministic
// prefix-sum). idx[b][j] ascending for j<cnt[b]; padded with 0 to 64-multiple.
__global__ void compact_kernel(const int* __restrict__ mask, int* __restrict__ idx,
                               int* __restrict__ cnt) {
  __shared__ int sc[256];
  const int b = blockIdx.x;
  const int t = threadIdx.x;
  const int* m = mask + b * TT;
  const int base = t * 8;
  int c = 0;
#pragma unroll
  for (int i = 0; i < 8; ++i) c += (m[base + i] != 0);
  sc[t] = c;
  __syncthreads();
  for (int off = 1; off < 256; off <<= 1) {
    int v = (t >= off) ? sc[t - off] : 0;
    __syncthreads();
    sc[t] += v;
    __syncthreads();
  }
  int pos = sc[t] - c;  // exclusive prefix
  int* ib = idx + b * TT;
#pragma unroll
  for (int i = 0; i < 8; ++i)
    if (m[base + i] != 0) ib[pos++] = base + i;
  if (t == 255) {
    int tot = sc[255];
    cnt[b] = tot;
    int totp = (tot + 63) & ~63;
    if (totp < 64) totp = 64;
    for (int j = tot; j < totp; ++j) ib[j] = 0;
  }
}

// C = (A_fp32 @ W^T + bias) * 0.125 * log2(e) ; query cvt fused (reg-stage A).
__launch_bounds__(256, 1)
__global__ void qproj_kernel(const float* __restrict__ A, const u16t* __restrict__ W,
                             const float* __restrict__ bias, u16t* __restrict__ C) {
  __shared__ u16t As[128 * 64];
  __shared__ u16t Bs[128 * 64];
  const int tid = threadIdx.x;
  const int m0 = blockIdx.x * 128;
  const int n0 = blockIdx.y * 128;
  const int w = tid >> 6, lane = tid & 63;
  const int wr = (w >> 1) * 64, wc = (w & 1) * 64;
  const int g = lane >> 4, r = lane & 15;

  f32x4 acc[4][4] = {};

  float4 a0[4], a1[4];
#pragma unroll
  for (int i = 0; i < 4; ++i) {
    int c = i * 256 + tid;
    int row = c >> 3, slot = c & 7;
    int gs = slot ^ (row & 7);
    const float* src = A + (size_t)(m0 + row) * NF + gs * 8;
    a0[i] = *reinterpret_cast<const float4*>(src);
    a1[i] = *reinterpret_cast<const float4*>(src + 4);
  }

  for (int kb = 0; kb < NF; kb += 64) {
    __syncthreads();
#pragma unroll
    for (int i = 0; i < 4; ++i) {
      int c = i * 256 + tid;
      int row = c >> 3, slot = c & 7;
      int gs = slot ^ (row & 7);
      __builtin_amdgcn_global_load_lds(GPTR(W + (size_t)(n0 + row) * NF + kb + gs * 8),
                                       LPTR(Bs + c * 8), 16, 0, 0);
    }
#pragma unroll
    for (int i = 0; i < 4; ++i) {
      int c = i * 256 + tid;
      union { u32t u[4]; int4 i4; } kw;
      kw.u[0] = pkbf(a0[i].x, a0[i].y);
      kw.u[1] = pkbf(a0[i].z, a0[i].w);
      kw.u[2] = pkbf(a1[i].x, a1[i].y);
      kw.u[3] = pkbf(a1[i].z, a1[i].w);
      *reinterpret_cast<int4*>(reinterpret_cast<char*>(As) + c * 16) = kw.i4;
    }
    __syncthreads();
    if (kb + 64 < NF) {
#pragma unroll
      for (int i = 0; i < 4; ++i) {
        int c = i * 256 + tid;
        int row = c >> 3, slot = c & 7;
        int gs = slot ^ (row & 7);
        const float* src = A + (size_t)(m0 + row) * NF + kb + 64 + gs * 8;
        a0[i] = *reinterpret_cast<const float4*>(src);
        a1[i] = *reinterpret_cast<const float4*>(src + 4);
      }
    }
#pragma unroll
    for (int kk = 0; kk < 2; ++kk) {
      short8 af[4], bfr[4];
#pragma unroll
      for (int i = 0; i < 4; ++i) {
        int row = wr + i * 16 + r;
        int slot = (4 * kk + g) ^ (row & 7);
        af[i] = *reinterpret_cast<const short8*>(As + row * 64 + slot * 8);
      }
#pragma unroll
      for (int j = 0; j < 4; ++j) {
        int row = wc + j * 16 + r;
        int slot = (4 * kk + g) ^ (row & 7);
        bfr[j] = *reinterpret_cast<const short8*>(Bs + row * 64 + slot * 8);
      }
#pragma unroll
      for (int i = 0; i < 4; ++i)
#pragma unroll
        for (int j = 0; j < 4; ++j)
          acc[i][j] = __builtin_amdgcn_mfma_f32_16x16x32_bf16(af[i], bfr[j], acc[i][j], 0, 0, 0);
    }
  }
#pragma unroll
  for (int i = 0; i < 4; ++i)
#pragma unroll
    for (int j = 0; j < 4; ++j) {
      int grow = m0 + wr + i * 16 + 4 * g;
      int gcol = n0 + wc + j * 16 + r;
      float bv = bias[gcol];
#pragma unroll
      for (int reg = 0; reg < 4; ++reg)
        C[(size_t)(grow + reg) * NF + gcol] = f2bf((acc[i][j][reg] + bv) * 0.18033688f);
    }
}

// Flash attention over COMPACTED kv (masked columns contribute exactly 0 and are
// skipped entirely — ~2x less work). R12 structure otherwise: swapped-QK^T, 8
// waves, 2 q-tiles/wave, counted-wait 1-barrier schedule, fused fp32 K/V staging
// via gathered rows idx[b][j]. Tail tile pads (j>=cnt) get -10000 C-init bias.
// LDS 32KB: K dbuf @0/@8192 (within-tile row j' 128B, 16B-slot s = granule
//   s^P(j'), P(r)=(r+(r>>3))&7); V dbuf @16384/@24576 (row d 128B, 8B-slot s =
//   j'-granule s^(d&15)^((d>>4)&3)).
__launch_bounds__(512, 2)
__global__ void attn_kernel(const u16t* __restrict__ Q, const float* __restrict__ K,
                            const float* __restrict__ V, const int* __restrict__ idx,
                            const int* __restrict__ cntArr, float* __restrict__ O) {
  __shared__ __attribute__((aligned(16))) char lds[32768];

  const int tid = threadIdx.x;
  const int lane = tid & 63;
  const int w = tid >> 6;
  const int qc = lane & 31;   // q-col for S^T / d-col for PV output
  const int hi = lane >> 5;
  const int b = blockIdx.x >> 4, h = blockIdx.x & 15;
  const size_t bbase = (size_t)b * TT * NF;
  const int hoff = h * DK;
  const int qrow0 = blockIdx.y * 512 + w * 32;   // q-tile 0; tile 1 at +256

  const int cnt = cntArr[b];
  int cntpad = (cnt + 63) & ~63;
  if (cntpad < 64) cntpad = 64;
  const int* ib = idx + b * TT;

  // Q B-frags (col=q=lane&31, k(d)=16t+8hi+e), both q-tiles, whole kernel
  short8 qa[2][4];
#pragma unroll
  for (int qt = 0; qt < 2; ++qt)
#pragma unroll
    for (int t = 0; t < 4; ++t)
      qa[qt][t] = *reinterpret_cast<const short8*>(
          Q + bbase + (size_t)(qrow0 + 256 * qt + qc) * NF + hoff + 16 * t + 8 * hi);

  f32x16 oacc[2][2] = {};
  float lsumA = 0.f, lsumB = 0.f;

  // K staging map: chunk = tid -> LDS tid*16; within-tile row tid>>3, granule swz
  const int srow = tid >> 3;
  const int ksg = (tid & 7) ^ ((srow + (srow >> 3)) & 7);
  // V staging map: thread = (Qv = tid>>5, sub = (tid>>4)&1, dq = tid&15)
  const int Qv = tid >> 5, sub = (tid >> 4) & 1, dq = tid & 15;
  const int slotbase = Qv ^ (dq >> 2) ^ (4 * (dq & 3));
  const int wbase = 4 * dq * 128 + (slotbase << 3) + 4 * sub;  // within V buffer

  // read-address bases (within buffers)
  const int P0 = (qc + (qc >> 3)) & 7;
  const int P1 = (P0 + 4) & 7;
  const int kB0 = qc * 128 + ((hi ^ P0) << 4);         // K row qc
  const int kB1 = qc * 128 + 4096 + ((hi ^ P1) << 4);  // K row qc+32
  const int g0 = hi ^ (qc & 15) ^ ((qc >> 4) & 3);
  const int vRb0 = qc * 128 + (g0 << 3);               // V col d=qc
  const int vRb1 = (qc + 32) * 128 + ((g0 ^ 2) << 3);  // V col d=qc+32

  // prologue: tile-0 gathered fp32 loads into registers (cvt deferred to write)
  float4 kf32a, kf32b, vf32a, vf32b;
  {
    int kj = ib[srow];
    const float* kp = K + bbase + (size_t)kj * NF + hoff + ksg * 8;
    kf32a = *reinterpret_cast<const float4*>(kp);
    kf32b = *reinterpret_cast<const float4*>(kp + 4);
    int vj0 = ib[4 * Qv + 2 * sub];
    int vj1 = ib[4 * Qv + 2 * sub + 1];
    vf32a = *reinterpret_cast<const float4*>(V + bbase + (size_t)vj0 * NF + hoff + 4 * dq);
    vf32b = *reinterpret_cast<const float4*>(V + bbase + (size_t)vj1 * NF + hoff + 4 * dq);
  }

  for (int t2 = 0; t2 < cntpad; t2 += 64) {
    const int cb = (t2 >> 6) & 1;
    const int kbb = cb * 8192;          // current K buffer
    const int vbb = 16384 + cb * 8192;  // current V buffer

    { // write K(t): cvt fp32->bf16 here
      union { u32t u[4]; int4 i4; } kw;
      kw.u[0] = pkbf(kf32a.x, kf32a.y);
      kw.u[1] = pkbf(kf32a.z, kf32a.w);
      kw.u[2] = pkbf(kf32b.x, kf32b.y);
      kw.u[3] = pkbf(kf32b.z, kf32b.w);
      *reinterpret_cast<int4*>(lds + kbb + tid * 16) = kw.i4;
    }
    { // write V(t): b64 granule (Qv, d), word sub
      u32t p0 = pkbf(vf32a.x, vf32b.x);
      u32t p1 = pkbf(vf32a.y, vf32b.y);
      u32t p2 = pkbf(vf32a.z, vf32b.z);
      u32t p3 = pkbf(vf32a.w, vf32b.w);
      *reinterpret_cast<u32t*>(lds + vbb + (wbase ^ 0) + 0) = p0;
      *reinterpret_cast<u32t*>(lds + vbb + (wbase ^ 8) + 128) = p1;
      *reinterpret_cast<u32t*>(lds + vbb + (wbase ^ 16) + 256) = p2;
      *reinterpret_cast<u32t*>(lds + vbb + (wbase ^ 24) + 384) = p3;
    }
    asm volatile("s_waitcnt vmcnt(0) lgkmcnt(0)" ::: "memory");
    __builtin_amdgcn_s_barrier();

    if (t2 + 64 < cntpad) {  // prefetch t+1 gathered fp32: whole compute(t) to land
      int kj = ib[t2 + 64 + srow];
      const float* kp = K + bbase + (size_t)kj * NF + hoff + ksg * 8;
      kf32a = *reinterpret_cast<const float4*>(kp);
      kf32b = *reinterpret_cast<const float4*>(kp + 4);
      int vj0 = ib[t2 + 64 + 4 * Qv + 2 * sub];
      int vj1 = ib[t2 + 64 + 4 * Qv + 2 * sub + 1];
      vf32a = *reinterpret_cast<const float4*>(V + bbase + (size_t)vj0 * NF + hoff + 4 * dq);
      vf32b = *reinterpret_cast<const float4*>(V + bbase + (size_t)vj1 * NF + hoff + 4 * dq);
    }

    // C-init: zero for full tiles; pad bias (-10000) only in the final tile
    f32x16 bias0 = {}, bias1 = {};
    if (t2 + 64 > cnt) {
#pragma unroll
      for (int reg = 0; reg < 16; ++reg) {
        const int j = t2 + (reg & 3) + 8 * (reg >> 2) + 4 * hi;
        bias0[reg] = (j < cnt) ? 0.f : -10000.f;
        bias1[reg] = (j + 32 < cnt) ? 0.f : -10000.f;
      }
    }

    // QK^T: K-frags shared across both q-tiles; t=0 seeds with bias
    f32x16 sA0, sA1, sB0, sB1;
    {
      short8 kf0 = *reinterpret_cast<const short8*>(lds + kbb + kB0);
      short8 kf1 = *reinterpret_cast<const short8*>(lds + kbb + kB1);
      sA0 = __builtin_amdgcn_mfma_f32_32x32x16_bf16(kf0, qa[0][0], bias0, 0, 0, 0);
      sA1 = __builtin_amdgcn_mfma_f32_32x32x16_bf16(kf1, qa[0][0], bias1, 0, 0, 0);
      sB0 = __builtin_amdgcn_mfma_f32_32x32x16_bf16(kf0, qa[1][0], bias0, 0, 0, 0);
      sB1 = __builtin_amdgcn_mfma_f32_32x32x16_bf16(kf1, qa[1][0], bias1, 0, 0, 0);
    }
#pragma unroll
    for (int t = 1; t < 4; ++t) {
      short8 kf0 = *reinterpret_cast<const short8*>(lds + kbb + (kB0 ^ (t << 5)));
      short8 kf1 = *reinterpret_cast<const short8*>(lds + kbb + (kB1 ^ (t << 5)));
      sA0 = __builtin_amdgcn_mfma_f32_32x32x16_bf16(kf0, qa[0][t], sA0, 0, 0, 0);
      sA1 = __builtin_amdgcn_mfma_f32_32x32x16_bf16(kf1, qa[0][t], sA1, 0, 0, 0);
      sB0 = __builtin_amdgcn_mfma_f32_32x32x16_bf16(kf0, qa[1][t], sB0, 0, 0, 0);
      sB1 = __builtin_amdgcn_mfma_f32_32x32x16_bf16(kf1, qa[1][t], sB1, 0, 0, 0);
    }

    // softmax + pack + PV per kv-16-slice t
#pragma unroll
    for (int t = 0; t < 4; ++t) {
      union { u32t u[4]; short8 s; } pA, pB;
      float eA = 0.f, eB = 0.f;
#pragma unroll
      for (int i = 0; i < 4; ++i) {
        const int reg = (t & 1) * 8 + 2 * i;
        float xa = __builtin_exp2f(t < 2 ? sA0[reg] : sA1[reg]);
        float xb = __builtin_exp2f(t < 2 ? sA0[reg + 1] : sA1[reg + 1]);
        float ya = __builtin_exp2f(t < 2 ? sB0[reg] : sB1[reg]);
        float yb = __builtin_exp2f(t < 2 ? sB0[reg + 1] : sB1[reg + 1]);
        eA += xa + xb; eB += ya + yb;
        pA.u[i] = pkbf(xa, xb);
        pB.u[i] = pkbf(ya, yb);
      }
      lsumA += eA; lsumB += eB;
      union { uint2 u2[2]; short8 s; } vf0, vf1;
      vf0.u2[0] = *reinterpret_cast<const uint2*>(lds + vbb + (vRb0 ^ ((4 * t) << 3)));
      vf0.u2[1] = *reinterpret_cast<const uint2*>(lds + vbb + (vRb0 ^ (((4 * t) ^ 2) << 3)));
      vf1.u2[0] = *reinterpret_cast<const uint2*>(lds + vbb + (vRb1 ^ ((4 * t) << 3)));
      vf1.u2[1] = *reinterpret_cast<const uint2*>(lds + vbb + (vRb1 ^ (((4 * t) ^ 2) << 3)));
      oacc[0][0] = __builtin_amdgcn_mfma_f32_32x32x16_bf16(pA.s, vf0.s, oacc[0][0], 0, 0, 0);
      oacc[0][1] = __builtin_amdgcn_mfma_f32_32x32x16_bf16(pA.s, vf1.s, oacc[0][1], 0, 0, 0);
      oacc[1][0] = __builtin_amdgcn_mfma_f32_32x32x16_bf16(pB.s, vf0.s, oacc[1][0], 0, 0, 0);
      oacc[1][1] = __builtin_amdgcn_mfma_f32_32x32x16_bf16(pB.s, vf1.s, oacc[1][1], 0, 0, 0);
    }
  }

  // O[q][d]: C-layout row = (reg&3)+8*(reg>>2)+4hi, col = qc (+32)
#pragma unroll
  for (int qt = 0; qt < 2; ++qt) {
    float lsq = qt ? lsumB : lsumA;
    float lall = lsq + __shfl_xor(lsq, 32, 64);
    float linv = (lall > 0.f) ? (1.0f / lall) : 0.f;
#pragma unroll
    for (int reg = 0; reg < 16; ++reg) {
      const int crow = (reg & 3) + 8 * (reg >> 2) + 4 * hi;
      float rl = __shfl(linv, crow, 64);
      float* orow = O + bbase + (size_t)(qrow0 + 256 * qt + crow) * NF + hoff + qc;
      orow[0] = oacc[qt][0][reg] * rl;
      orow[32] = oacc[qt][1][reg] * rl;
    }
  }
}

extern "C" void kernel_launch(void* const* d_in, const int* in_sizes, int n_in,
                              void* d_out, int out_size, void* d_ws, size_t ws_size,
                              hipStream_t stream) {
  const float* query = (const float*)d_in[0];
  const float* key   = (const float*)d_in[1];
  const float* value = (const float*)d_in[2];
  const int*   mask  = (const int*)d_in[3];
  const float* Wq    = (const float*)d_in[4];
  const float* bq    = (const float*)d_in[5];
  float* out = (float*)d_out;

  u16t* ws = (u16t*)d_ws;
  u16t* wb = ws;                                   // bf16 Wq     (1M elems)
  u16t* qp = ws + (size_t)1024 * 1024;             // bf16 q-proj (8M elems)
  int* idx = (int*)(ws + (size_t)9 * 1024 * 1024); // 4*2048 ints
  int* cnt = idx + BB * TT;                        // 4 ints

  compact_kernel<<<BB, 256, 0, stream>>>(mask, idx, cnt);
  cvt_kernel<<<1024, 256, 0, stream>>>(Wq, wb, (NF * NF) / 4);

  qproj_kernel<<<dim3(BT / 128, NF / 128), 256, 0, stream>>>(query, wb, bq, qp);
  // grid: x = (b,h), y = q-pair; 4 q-blocks of one (b,h) share an XCD (flat%8 = x%8)
  attn_kernel<<<dim3(BB * NHEAD, TT / 512), 512, 0, stream>>>(qp, key, value, idx, cnt, out);
}